// Round 1
// baseline (363.342 us; speedup 1.0000x reference)
//
#include <hip/hip_runtime.h>
#include <hip/hip_bf16.h>
#include <stdint.h>

// GWNN: out = L2(relu(L1(x))),  L(x) = W_wav · diag(f) · W_inv · (x·W)
// 4 big GEMMs (8192x128x8192) A=fp32 wavelets from HBM (cvt->bf16 at LDS read),
// B = transposed bf16 intermediates in ws (L2-resident). Counted-vmcnt
// double-buffered global_load_lds pipeline, XOR-swizzled LDS.

typedef __attribute__((ext_vector_type(4))) float f32x4;
typedef __attribute__((ext_vector_type(8))) short s16x8;
typedef __attribute__((ext_vector_type(4))) short s16x4;

#define DEVI static __device__ __forceinline__

DEVI short bf1(float x){ __bf16 h = (__bf16)x; return __builtin_bit_cast(short, h); }

DEVI s16x8 cvt8(f32x4 lo, f32x4 hi){
  s16x8 r;
#pragma unroll
  for (int i = 0; i < 4; ++i){ r[i] = bf1(lo[i]); r[4+i] = bf1(hi[i]); }
  return r;
}

DEVI void glds16(const void* g, void* l){
  __builtin_amdgcn_global_load_lds((const __attribute__((address_space(1))) void*)g,
                                   (__attribute__((address_space(3))) void*)l, 16, 0, 0);
}

template<int N> DEVI void waitvm(){
  if constexpr (N == 0) asm volatile("s_waitcnt vmcnt(0)" ::: "memory");
  else if constexpr (N == 5) asm volatile("s_waitcnt vmcnt(5)" ::: "memory");
  else asm volatile("s_waitcnt vmcnt(6)" ::: "memory");
}

// C[M,128] = A[M,K] @ Bt[128,K]^T ;  A fp32 (ABF=0) or bf16 (ABF=1) row-major,
// Bt bf16 row-major [128][K]. OUTM: 0 = f32 row-major, 1 = bf16 row-major,
// 2 = bf16 transposed [128][M]. SCALE: multiply row m by fp[m]. RELU on store.
template<bool ABF, bool SCALE, bool RELU, int OUTM>
__global__ __launch_bounds__(256, 1) void gemm_k(
    const void* __restrict__ Ap, const short* __restrict__ Btp,
    const float* __restrict__ fp, void* __restrict__ Outp, int K, int M)
{
  constexpr int BM = 32, BN = 128, BK = 64;
  constexpr int ASZ = ABF ? BM*BK*2 : BM*BK*4;   // A tile bytes (bf16 or fp32)
  constexpr int BSZ = BN*BK*2;                    // 16 KB
  constexpr int NL  = ABF ? 5 : 6;                // global_load_lds per wave per stage
  __shared__ uint8_t lds[2*(ASZ+BSZ)];

  const int tid  = threadIdx.x;
  const int lane = tid & 63;
  const int wv   = tid >> 6;
  const int la   = lane & 15;
  const int g4   = lane >> 4;
  const int m0   = blockIdx.x * BM;

  // ---- staging pointers (global source pre-swizzled; LDS dest stays linear)
  const float* gA0 = nullptr; const float* gA1 = nullptr; const short* gAh = nullptr;
  if constexpr (!ABF){
    const float* Af = (const float*)Ap;
    int r0 = (wv<<3) + (lane>>4);            // rows 8w..8w+3 (j=0)
    int r1 = r0 + 4;                          // rows 8w+4..8w+7 (j=1)
    gA0 = Af + (size_t)(m0+r0)*K + (((lane&15)^(r0&15))<<2);
    gA1 = Af + (size_t)(m0+r1)*K + (((lane&15)^(r1&15))<<2);
  } else {
    const short* Ah = (const short*)Ap;
    int r = (wv<<3) + (lane>>3);
    gAh = Ah + (size_t)(m0+r)*K + (((lane&7)^(r&7))<<3);
  }
  const int nb0 = (wv<<5) + (lane>>3);       // B rows: wave stages n = 32w..32w+31
  const short* gB0 = Btp + (size_t)(nb0    )*K + (((lane&7)^(nb0&7))<<3);
  const short* gB1 = Btp + (size_t)(nb0+ 8 )*K + (((lane&7)^(nb0&7))<<3);
  const short* gB2 = Btp + (size_t)(nb0+16 )*K + (((lane&7)^(nb0&7))<<3);
  const short* gB3 = Btp + (size_t)(nb0+24 )*K + (((lane&7)^(nb0&7))<<3);

  // ---- fragment LDS byte offsets (XOR-swizzled reads)
  int aoff[2][2][2];   // [mi][kf][part]
  int boff[2][2];      // [ni][kf]
#pragma unroll
  for (int mi = 0; mi < 2; ++mi){
    const int r = mi*16 + la;
#pragma unroll
    for (int kf = 0; kf < 2; ++kf){
      if constexpr (!ABF){
        const int v0 = kf*8 + (g4<<1);                  // 16B unit (fp32 row = 16 units)
        aoff[mi][kf][0] = r*256 + (((v0  )^(r&15))<<4);
        aoff[mi][kf][1] = r*256 + (((v0+1)^(r&15))<<4);
      } else {
        const int u = kf*4 + g4;                        // 16B unit (bf16 row = 8 units)
        aoff[mi][kf][0] = r*128 + ((u^(r&7))<<4);
        aoff[mi][kf][1] = 0;
      }
    }
  }
#pragma unroll
  for (int ni = 0; ni < 2; ++ni){
    const int n = (wv<<5) + ni*16 + la;
#pragma unroll
    for (int kf = 0; kf < 2; ++kf){
      const int u = kf*4 + g4;
      boff[ni][kf] = n*128 + ((u^(n&7))<<4);
    }
  }

  f32x4 acc[2][2] = {};

  auto STAGE = [&](int buf){
    uint8_t* Ab = &lds[buf*(ASZ+BSZ)];
    uint8_t* Bb = Ab + ASZ;
    if constexpr (!ABF){
      glds16(gA0, Ab + (wv<<11));
      glds16(gA1, Ab + (wv<<11) + 1024);
      gA0 += BK; gA1 += BK;
    } else {
      glds16(gAh, Ab + (wv<<10));
      gAh += BK;
    }
    glds16(gB0, Bb + (wv<<12));
    glds16(gB1, Bb + (wv<<12) + 1024);
    glds16(gB2, Bb + (wv<<12) + 2048);
    glds16(gB3, Bb + (wv<<12) + 3072);
    gB0 += BK; gB1 += BK; gB2 += BK; gB3 += BK;
  };

  auto COMPUTE = [&](int buf){
    const uint8_t* Ab = &lds[buf*(ASZ+BSZ)];
    const uint8_t* Bb = Ab + ASZ;
#pragma unroll
    for (int kf = 0; kf < 2; ++kf){
      s16x8 a0, a1, b0, b1;
      if constexpr (!ABF){
        a0 = cvt8(*(const f32x4*)(Ab + aoff[0][kf][0]), *(const f32x4*)(Ab + aoff[0][kf][1]));
        a1 = cvt8(*(const f32x4*)(Ab + aoff[1][kf][0]), *(const f32x4*)(Ab + aoff[1][kf][1]));
      } else {
        a0 = *(const s16x8*)(Ab + aoff[0][kf][0]);
        a1 = *(const s16x8*)(Ab + aoff[1][kf][0]);
      }
      b0 = *(const s16x8*)(Bb + boff[0][kf]);
      b1 = *(const s16x8*)(Bb + boff[1][kf]);
      acc[0][0] = __builtin_amdgcn_mfma_f32_16x16x32_bf16(a0, b0, acc[0][0], 0, 0, 0);
      acc[0][1] = __builtin_amdgcn_mfma_f32_16x16x32_bf16(a0, b1, acc[0][1], 0, 0, 0);
      acc[1][0] = __builtin_amdgcn_mfma_f32_16x16x32_bf16(a1, b0, acc[1][0], 0, 0, 0);
      acc[1][1] = __builtin_amdgcn_mfma_f32_16x16x32_bf16(a1, b1, acc[1][1], 0, 0, 0);
    }
  };

  const int nsteps = K >> 6;
  STAGE(0);
  for (int t = 0; t < nsteps; ++t){
    const int cur = t & 1;
    if (t + 1 < nsteps){ STAGE(cur ^ 1); waitvm<NL>(); }
    else               { waitvm<0>(); }
    __builtin_amdgcn_s_barrier();
    asm volatile("" ::: "memory");
    COMPUTE(cur);
    asm volatile("" ::: "memory");
    __builtin_amdgcn_s_barrier();   // protect buffer about to be restaged
  }

  // ---- epilogue
  const int mbase = m0 + (g4<<2);
  const int nc0   = (wv<<5) + la;
  f32x4 fv0, fv1;
  if constexpr (SCALE){
    fv0 = *(const f32x4*)(fp + mbase);
    fv1 = *(const f32x4*)(fp + mbase + 16);
  }
#pragma unroll
  for (int mi = 0; mi < 2; ++mi){
#pragma unroll
    for (int ni = 0; ni < 2; ++ni){
      f32x4 v = acc[mi][ni];
      if constexpr (SCALE) v = v * (mi ? fv1 : fv0);
      if constexpr (RELU){
#pragma unroll
        for (int r = 0; r < 4; ++r) v[r] = fmaxf(v[r], 0.0f);
      }
      if constexpr (OUTM == 2){
        s16x4 pk;
#pragma unroll
        for (int r = 0; r < 4; ++r) pk[r] = bf1(v[r]);
        *(s16x4*)((short*)Outp + (size_t)(nc0 + (ni<<4))*M + (mbase + (mi<<4))) = pk;
      } else if constexpr (OUTM == 1){
#pragma unroll
        for (int r = 0; r < 4; ++r)
          ((short*)Outp)[(size_t)(mbase + (mi<<4) + r)*BN + nc0 + (ni<<4)] = bf1(v[r]);
      } else {
#pragma unroll
        for (int r = 0; r < 4; ++r)
          ((float*)Outp)[(size_t)(mbase + (mi<<4) + r)*BN + nc0 + (ni<<4)] = v[r];
      }
    }
  }
}

// W1T[n][k] = bf16(W1[k][n]), same for W2 — tiny one-shot transpose.
__global__ void wtrans_k(const float* __restrict__ W1, const float* __restrict__ W2,
                         short* __restrict__ T1, short* __restrict__ T2){
  const int idx = blockIdx.x*256 + threadIdx.x;   // 32768 threads
  const int m = idx >> 14, rem = idx & 16383;
  const int n = rem >> 7, k = rem & 127;
  const float* W = m ? W2 : W1;
  short* T = m ? T2 : T1;
  T[n*128 + k] = bf1(W[k*128 + n]);
}

extern "C" void kernel_launch(void* const* d_in, const int* in_sizes, int n_in,
                              void* d_out, int out_size, void* d_ws, size_t ws_size,
                              hipStream_t stream){
  const float* input = (const float*)d_in[0];
  const float* wav   = (const float*)d_in[1];
  const float* winv  = (const float*)d_in[2];
  const float* W1    = (const float*)d_in[3];
  const float* f1    = (const float*)d_in[4];
  const float* W2    = (const float*)d_in[5];
  const float* f2    = (const float*)d_in[6];

  uint8_t* ws = (uint8_t*)d_ws;
  short* W1T = (short*)(ws);                        // 32 KB
  short* W2T = (short*)(ws + (32<<10));             // 32 KB
  short* XWT = (short*)(ws + (64<<10));             // 2 MB  (XW1T then XW2T)
  short* SPT = (short*)(ws + (64<<10) + (2<<20));   // 2 MB  (spec1T then spec2T)
  short* H1  = (short*)(ws + (64<<10) + (4<<20));   // 2 MB  bf16 row-major

  constexpr int M = 8192;
  dim3 b(256), g(M/32), gt(128);

  wtrans_k<<<gt, b, 0, stream>>>(W1, W2, W1T, W2T);
  // layer 1
  gemm_k<false,false,false,2><<<g,b,0,stream>>>(input, W1T, nullptr, XWT, 128, M);
  gemm_k<false,true ,false,2><<<g,b,0,stream>>>(winv,  XWT, f1,      SPT, M,   M);
  gemm_k<false,false,true ,1><<<g,b,0,stream>>>(wav,   SPT, nullptr, H1,  M,   M);
  // layer 2
  gemm_k<true ,false,false,2><<<g,b,0,stream>>>(H1,    W2T, nullptr, XWT, 128, M);
  gemm_k<false,true ,false,2><<<g,b,0,stream>>>(winv,  XWT, f2,      SPT, M,   M);
  gemm_k<false,false,false,0><<<g,b,0,stream>>>(wav,   SPT, nullptr, d_out, M, M);
}

// Round 2
// 319.696 us; speedup vs baseline: 1.1365x; 1.1365x over previous
//
#include <hip/hip_runtime.h>
#include <hip/hip_bf16.h>
#include <stdint.h>

// GWNN: out = L2(relu(L1(x))),  L(x) = W_wav · diag(f) · W_inv · (x·W)
// 4 big GEMMs (8192x128x8192) A=fp32 wavelets from HBM (cvt->bf16 at LDS read),
// B = transposed bf16 intermediates in ws (L2-resident).
// R2: 4-deep LDS buffer ring, 3 stages in flight, counted vmcnt (T3/T4),
//     one barrier per K-step. Target: HBM-BW-bound big GEMMs (~43us each).

typedef __attribute__((ext_vector_type(4))) float f32x4;
typedef __attribute__((ext_vector_type(8))) short s16x8;
typedef __attribute__((ext_vector_type(4))) short s16x4;

#define DEVI static __device__ __forceinline__

DEVI short bf1(float x){ __bf16 h = (__bf16)x; return __builtin_bit_cast(short, h); }

DEVI s16x8 cvt8(f32x4 lo, f32x4 hi){
  s16x8 r;
#pragma unroll
  for (int i = 0; i < 4; ++i){ r[i] = bf1(lo[i]); r[4+i] = bf1(hi[i]); }
  return r;
}

DEVI void glds16(const void* g, void* l){
  __builtin_amdgcn_global_load_lds((const __attribute__((address_space(1))) void*)g,
                                   (__attribute__((address_space(3))) void*)l, 16, 0, 0);
}

template<int N> DEVI void waitvm(){
  if constexpr (N == 0)       asm volatile("s_waitcnt vmcnt(0)"  ::: "memory");
  else if constexpr (N == 5)  asm volatile("s_waitcnt vmcnt(5)"  ::: "memory");
  else if constexpr (N == 6)  asm volatile("s_waitcnt vmcnt(6)"  ::: "memory");
  else if constexpr (N == 10) asm volatile("s_waitcnt vmcnt(10)" ::: "memory");
  else                        asm volatile("s_waitcnt vmcnt(12)" ::: "memory");
}

// C[M,128] = A[M,K] @ Bt[128,K]^T ;  A fp32 (ABF=0) or bf16 (ABF=1) row-major,
// Bt bf16 row-major [128][K]. OUTM: 0 = f32 row-major, 1 = bf16 row-major,
// 2 = bf16 transposed [128][M]. SCALE: multiply row m by fp[m]. RELU on store.
template<bool ABF, bool SCALE, bool RELU, int OUTM>
__global__ __launch_bounds__(256, 1) void gemm_k(
    const void* __restrict__ Ap, const short* __restrict__ Btp,
    const float* __restrict__ fp, void* __restrict__ Outp, int K, int M)
{
  constexpr int BM = 32, BN = 128, BK = 64;
  constexpr int ASZ = ABF ? BM*BK*2 : BM*BK*4;   // A tile bytes (bf16 or fp32)
  constexpr int BSZ = BN*BK*2;                    // 16 KB
  constexpr int NL  = ABF ? 5 : 6;                // global_load_lds per wave per stage
  constexpr int NBUF = 4;                         // ring depth (3 stages in flight)
  __shared__ uint8_t lds[NBUF*(ASZ+BSZ)];

  const int tid  = threadIdx.x;
  const int lane = tid & 63;
  const int wv   = tid >> 6;
  const int la   = lane & 15;
  const int g4   = lane >> 4;
  const int m0   = blockIdx.x * BM;

  // ---- staging pointers (global source pre-swizzled; LDS dest stays linear)
  const float* gA0 = nullptr; const float* gA1 = nullptr; const short* gAh = nullptr;
  if constexpr (!ABF){
    const float* Af = (const float*)Ap;
    int r0 = (wv<<3) + (lane>>4);            // rows 8w..8w+3 (j=0)
    int r1 = r0 + 4;                          // rows 8w+4..8w+7 (j=1)
    gA0 = Af + (size_t)(m0+r0)*K + (((lane&15)^(r0&15))<<2);
    gA1 = Af + (size_t)(m0+r1)*K + (((lane&15)^(r1&15))<<2);
  } else {
    const short* Ah = (const short*)Ap;
    int r = (wv<<3) + (lane>>3);
    gAh = Ah + (size_t)(m0+r)*K + (((lane&7)^(r&7))<<3);
  }
  const int nb0 = (wv<<5) + (lane>>3);       // B rows: wave stages n = 32w..32w+31
  const short* gB0 = Btp + (size_t)(nb0    )*K + (((lane&7)^(nb0&7))<<3);
  const short* gB1 = Btp + (size_t)(nb0+ 8 )*K + (((lane&7)^(nb0&7))<<3);
  const short* gB2 = Btp + (size_t)(nb0+16 )*K + (((lane&7)^(nb0&7))<<3);
  const short* gB3 = Btp + (size_t)(nb0+24 )*K + (((lane&7)^(nb0&7))<<3);

  // ---- fragment LDS byte offsets (XOR-swizzled reads)
  int aoff[2][2][2];   // [mi][kf][part]
  int boff[2][2];      // [ni][kf]
#pragma unroll
  for (int mi = 0; mi < 2; ++mi){
    const int r = mi*16 + la;
#pragma unroll
    for (int kf = 0; kf < 2; ++kf){
      if constexpr (!ABF){
        const int v0 = kf*8 + (g4<<1);                  // 16B unit (fp32 row = 16 units)
        aoff[mi][kf][0] = r*256 + (((v0  )^(r&15))<<4);
        aoff[mi][kf][1] = r*256 + (((v0+1)^(r&15))<<4);
      } else {
        const int u = kf*4 + g4;                        // 16B unit (bf16 row = 8 units)
        aoff[mi][kf][0] = r*128 + ((u^(r&7))<<4);
        aoff[mi][kf][1] = 0;
      }
    }
  }
#pragma unroll
  for (int ni = 0; ni < 2; ++ni){
    const int n = (wv<<5) + ni*16 + la;
#pragma unroll
    for (int kf = 0; kf < 2; ++kf){
      const int u = kf*4 + g4;
      boff[ni][kf] = n*128 + ((u^(n&7))<<4);
    }
  }

  f32x4 acc[2][2] = {};

  auto STAGE = [&](int buf){
    uint8_t* Ab = &lds[buf*(ASZ+BSZ)];
    uint8_t* Bb = Ab + ASZ;
    if constexpr (!ABF){
      glds16(gA0, Ab + (wv<<11));
      glds16(gA1, Ab + (wv<<11) + 1024);
      gA0 += BK; gA1 += BK;
    } else {
      glds16(gAh, Ab + (wv<<10));
      gAh += BK;
    }
    glds16(gB0, Bb + (wv<<12));
    glds16(gB1, Bb + (wv<<12) + 1024);
    glds16(gB2, Bb + (wv<<12) + 2048);
    glds16(gB3, Bb + (wv<<12) + 3072);
    gB0 += BK; gB1 += BK; gB2 += BK; gB3 += BK;
  };

  auto COMPUTE = [&](int buf){
    const uint8_t* Ab = &lds[buf*(ASZ+BSZ)];
    const uint8_t* Bb = Ab + ASZ;
#pragma unroll
    for (int kf = 0; kf < 2; ++kf){
      s16x8 a0, a1, b0, b1;
      if constexpr (!ABF){
        a0 = cvt8(*(const f32x4*)(Ab + aoff[0][kf][0]), *(const f32x4*)(Ab + aoff[0][kf][1]));
        a1 = cvt8(*(const f32x4*)(Ab + aoff[1][kf][0]), *(const f32x4*)(Ab + aoff[1][kf][1]));
      } else {
        a0 = *(const s16x8*)(Ab + aoff[0][kf][0]);
        a1 = *(const s16x8*)(Ab + aoff[1][kf][0]);
      }
      b0 = *(const s16x8*)(Bb + boff[0][kf]);
      b1 = *(const s16x8*)(Bb + boff[1][kf]);
      acc[0][0] = __builtin_amdgcn_mfma_f32_16x16x32_bf16(a0, b0, acc[0][0], 0, 0, 0);
      acc[0][1] = __builtin_amdgcn_mfma_f32_16x16x32_bf16(a0, b1, acc[0][1], 0, 0, 0);
      acc[1][0] = __builtin_amdgcn_mfma_f32_16x16x32_bf16(a1, b0, acc[1][0], 0, 0, 0);
      acc[1][1] = __builtin_amdgcn_mfma_f32_16x16x32_bf16(a1, b1, acc[1][1], 0, 0, 0);
    }
  };

  const int nsteps = K >> 6;
  // prologue: fill the pipeline 3 deep
  for (int s = 0; s < 3 && s < nsteps; ++s) STAGE(s & (NBUF-1));

  for (int t = 0; t < nsteps; ++t){
    const int ahead = nsteps - 1 - t;      // stages still in flight beyond t
    if (ahead >= 2)      waitvm<2*NL>();   // stage t guaranteed complete
    else if (ahead == 1) waitvm<NL>();
    else                 waitvm<0>();
    __builtin_amdgcn_s_barrier();          // publishes stage t; gates restage of buf (t-1)
    asm volatile("" ::: "memory");
    if (t + 3 < nsteps) STAGE((t + 3) & (NBUF-1));
    COMPUTE(t & (NBUF-1));
    asm volatile("" ::: "memory");
  }

  // ---- epilogue
  const int mbase = m0 + (g4<<2);
  const int nc0   = (wv<<5) + la;
  f32x4 fv0, fv1;
  if constexpr (SCALE){
    fv0 = *(const f32x4*)(fp + mbase);
    fv1 = *(const f32x4*)(fp + mbase + 16);
  }
#pragma unroll
  for (int mi = 0; mi < 2; ++mi){
#pragma unroll
    for (int ni = 0; ni < 2; ++ni){
      f32x4 v = acc[mi][ni];
      if constexpr (SCALE) v = v * (mi ? fv1 : fv0);
      if constexpr (RELU){
#pragma unroll
        for (int r = 0; r < 4; ++r) v[r] = fmaxf(v[r], 0.0f);
      }
      if constexpr (OUTM == 2){
        s16x4 pk;
#pragma unroll
        for (int r = 0; r < 4; ++r) pk[r] = bf1(v[r]);
        *(s16x4*)((short*)Outp + (size_t)(nc0 + (ni<<4))*M + (mbase + (mi<<4))) = pk;
      } else if constexpr (OUTM == 1){
#pragma unroll
        for (int r = 0; r < 4; ++r)
          ((short*)Outp)[(size_t)(mbase + (mi<<4) + r)*BN + nc0 + (ni<<4)] = bf1(v[r]);
      } else {
#pragma unroll
        for (int r = 0; r < 4; ++r)
          ((float*)Outp)[(size_t)(mbase + (mi<<4) + r)*BN + nc0 + (ni<<4)] = v[r];
      }
    }
  }
}

// W1T[n][k] = bf16(W1[k][n]), same for W2 — tiny one-shot transpose.
__global__ void wtrans_k(const float* __restrict__ W1, const float* __restrict__ W2,
                         short* __restrict__ T1, short* __restrict__ T2){
  const int idx = blockIdx.x*256 + threadIdx.x;   // 32768 threads
  const int m = idx >> 14, rem = idx & 16383;
  const int n = rem >> 7, k = rem & 127;
  const float* W = m ? W2 : W1;
  short* T = m ? T2 : T1;
  T[n*128 + k] = bf1(W[k*128 + n]);
}

extern "C" void kernel_launch(void* const* d_in, const int* in_sizes, int n_in,
                              void* d_out, int out_size, void* d_ws, size_t ws_size,
                              hipStream_t stream){
  const float* input = (const float*)d_in[0];
  const float* wav   = (const float*)d_in[1];
  const float* winv  = (const float*)d_in[2];
  const float* W1    = (const float*)d_in[3];
  const float* f1    = (const float*)d_in[4];
  const float* W2    = (const float*)d_in[5];
  const float* f2    = (const float*)d_in[6];

  uint8_t* ws = (uint8_t*)d_ws;
  short* W1T = (short*)(ws);                        // 32 KB
  short* W2T = (short*)(ws + (32<<10));             // 32 KB
  short* XWT = (short*)(ws + (64<<10));             // 2 MB  (XW1T then XW2T)
  short* SPT = (short*)(ws + (64<<10) + (2<<20));   // 2 MB  (spec1T then spec2T)
  short* H1  = (short*)(ws + (64<<10) + (4<<20));   // 2 MB  bf16 row-major

  constexpr int M = 8192;
  dim3 b(256), g(M/32), gt(128);

  wtrans_k<<<gt, b, 0, stream>>>(W1, W2, W1T, W2T);
  // layer 1
  gemm_k<false,false,false,2><<<g,b,0,stream>>>(input, W1T, nullptr, XWT, 128, M);
  gemm_k<false,true ,false,2><<<g,b,0,stream>>>(winv,  XWT, f1,      SPT, M,   M);
  gemm_k<false,false,true ,1><<<g,b,0,stream>>>(wav,   SPT, nullptr, H1,  M,   M);
  // layer 2
  gemm_k<true ,false,false,2><<<g,b,0,stream>>>(H1,    W2T, nullptr, XWT, 128, M);
  gemm_k<false,true ,false,2><<<g,b,0,stream>>>(winv,  XWT, f2,      SPT, M,   M);
  gemm_k<false,false,false,0><<<g,b,0,stream>>>(wav,   SPT, nullptr, d_out, M, M);
}